// Round 2
// baseline (177.723 us; speedup 1.0000x reference)
//
#include <hip/hip_runtime.h>
#include <hip/hip_bf16.h>

#define BATCH 65536
#define IN    64
#define H     128
#define NA    16
#define HPAD  136   // 128 + 8 pad: 272B row stride, 16B-aligned

typedef __bf16 bf16x8 __attribute__((ext_vector_type(8)));
typedef float  f32x4  __attribute__((ext_vector_type(4)));

union Frag { uint4 u; bf16x8 v; };

__device__ __forceinline__ float fast_sigmoid(float x) { return 1.0f / (1.0f + __expf(-x)); }
__device__ __forceinline__ float fast_tanh(float x)    { return 2.0f / (1.0f + __expf(-2.0f * x)) - 1.0f; }

// ---- dtype-generic load/store: convert to bf16 fragments / f32 scalars ----
template<typename T> struct LD;

template<> struct LD<__hip_bfloat16> {
    static __device__ __forceinline__ Frag load8(const void* base, size_t off) {
        Frag f;
        f.u = *reinterpret_cast<const uint4*>(reinterpret_cast<const __hip_bfloat16*>(base) + off);
        return f;
    }
    static __device__ __forceinline__ float ld1(const void* base, size_t i) {
        return __bfloat162float(reinterpret_cast<const __hip_bfloat16*>(base)[i]);
    }
    static __device__ __forceinline__ void st1(void* base, size_t i, float v) {
        reinterpret_cast<__hip_bfloat16*>(base)[i] = __float2bfloat16(v);
    }
};

template<> struct LD<float> {
    static __device__ __forceinline__ Frag load8(const void* base, size_t off) {
        const float* p = reinterpret_cast<const float*>(base) + off;
        float4 a = *reinterpret_cast<const float4*>(p);
        float4 b = *reinterpret_cast<const float4*>(p + 4);
        Frag f;
        f.v[0] = (__bf16)a.x; f.v[1] = (__bf16)a.y; f.v[2] = (__bf16)a.z; f.v[3] = (__bf16)a.w;
        f.v[4] = (__bf16)b.x; f.v[5] = (__bf16)b.y; f.v[6] = (__bf16)b.z; f.v[7] = (__bf16)b.w;
        return f;
    }
    static __device__ __forceinline__ float ld1(const void* base, size_t i) {
        return reinterpret_cast<const float*>(base)[i];
    }
    static __device__ __forceinline__ void st1(void* base, size_t i, float v) {
        reinterpret_cast<float*>(base)[i] = v;
    }
};

// MT: dtype of x / weight matrices / output; BT: dtype of bias vectors
template<typename MT, typename BT>
__device__ __forceinline__ void run_net(
    const void* x, const void* Wih0, const void* bih0, const void* bhh0,
    const void* Wih1, const void* bih1, const void* bhh1,
    const void* Wp, const void* bp, const void* Wv, const void* bv,
    void* out, __hip_bfloat16* hb, int lane, int rowblk)
{
    const int m16  = lane & 15;   // A-row / B-col / C-col
    const int quad = lane >> 4;   // 0..3
    const f32x4 vzero = {0.f, 0.f, 0.f, 0.f};
    const int kGoff[3] = {0, 2 * H, 3 * H};   // gates i, g, o (f dead: c_prev = 0)

    // ========== GEMM1: gates0 = x @ Wih0[igo]^T ; h0 -> LDS ==========
    Frag a1[4][2];
#pragma unroll
    for (int s = 0; s < 4; ++s)
#pragma unroll
        for (int kt = 0; kt < 2; ++kt)
            a1[s][kt] = LD<MT>::load8(x, (size_t)(rowblk + s * 16 + m16) * IN + kt * 32 + quad * 8);

#pragma unroll
    for (int c = 0; c < 8; ++c) {
        f32x4 acc[3][4];
#pragma unroll
        for (int G = 0; G < 3; ++G)
#pragma unroll
            for (int s = 0; s < 4; ++s) acc[G][s] = vzero;

#pragma unroll
        for (int G = 0; G < 3; ++G) {
            const int wrow = kGoff[G] + c * 16 + m16;
#pragma unroll
            for (int kt = 0; kt < 2; ++kt) {
                Frag b = LD<MT>::load8(Wih0, (size_t)wrow * IN + kt * 32 + quad * 8);
#pragma unroll
                for (int s = 0; s < 4; ++s)
                    acc[G][s] = __builtin_amdgcn_mfma_f32_16x16x32_bf16(a1[s][kt].v, b.v, acc[G][s], 0, 0, 0);
            }
        }

        float bi[3];
#pragma unroll
        for (int G = 0; G < 3; ++G) {
            const int n = kGoff[G] + c * 16 + m16;
            bi[G] = LD<BT>::ld1(bih0, n) + LD<BT>::ld1(bhh0, n);
        }

#pragma unroll
        for (int s = 0; s < 4; ++s)
#pragma unroll
            for (int r = 0; r < 4; ++r) {
                const float ii = fast_sigmoid(acc[0][s][r] + bi[0]);
                const float gg = fast_tanh   (acc[1][s][r] + bi[1]);
                const float oo = fast_sigmoid(acc[2][s][r] + bi[2]);
                const float h  = oo * fast_tanh(ii * gg);
                hb[(s * 16 + quad * 4 + r) * HPAD + c * 16 + m16] = __float2bfloat16(h);
            }
    }

    // ========== GEMM2: gates1 = h0 @ Wih1[igo]^T ; h1 -> LDS ==========
    Frag a2[4][4];
#pragma unroll
    for (int s = 0; s < 4; ++s)
#pragma unroll
        for (int kt = 0; kt < 4; ++kt)
            a2[s][kt].u = *reinterpret_cast<const uint4*>(hb + (s * 16 + m16) * HPAD + kt * 32 + quad * 8);

#pragma unroll
    for (int c = 0; c < 8; ++c) {
        f32x4 acc[3][4];
#pragma unroll
        for (int G = 0; G < 3; ++G)
#pragma unroll
            for (int s = 0; s < 4; ++s) acc[G][s] = vzero;

#pragma unroll
        for (int G = 0; G < 3; ++G) {
            const int wrow = kGoff[G] + c * 16 + m16;
#pragma unroll
            for (int kt = 0; kt < 4; ++kt) {
                Frag b = LD<MT>::load8(Wih1, (size_t)wrow * H + kt * 32 + quad * 8);
#pragma unroll
                for (int s = 0; s < 4; ++s)
                    acc[G][s] = __builtin_amdgcn_mfma_f32_16x16x32_bf16(a2[s][kt].v, b.v, acc[G][s], 0, 0, 0);
            }
        }

        float bi[3];
#pragma unroll
        for (int G = 0; G < 3; ++G) {
            const int n = kGoff[G] + c * 16 + m16;
            bi[G] = LD<BT>::ld1(bih1, n) + LD<BT>::ld1(bhh1, n);
        }

#pragma unroll
        for (int s = 0; s < 4; ++s)
#pragma unroll
            for (int r = 0; r < 4; ++r) {
                const float ii = fast_sigmoid(acc[0][s][r] + bi[0]);
                const float gg = fast_tanh   (acc[1][s][r] + bi[1]);
                const float oo = fast_sigmoid(acc[2][s][r] + bi[2]);
                const float h  = oo * fast_tanh(ii * gg);
                hb[(s * 16 + quad * 4 + r) * HPAD + c * 16 + m16] = __float2bfloat16(h);
            }
    }

    // ========== GEMM3: policy + value heads ==========
    Frag a3[4][4];
#pragma unroll
    for (int s = 0; s < 4; ++s)
#pragma unroll
        for (int kt = 0; kt < 4; ++kt)
            a3[s][kt].u = *reinterpret_cast<const uint4*>(hb + (s * 16 + m16) * HPAD + kt * 32 + quad * 8);

    Frag bpf[4];
#pragma unroll
    for (int kt = 0; kt < 4; ++kt)
        bpf[kt] = LD<MT>::load8(Wp, (size_t)m16 * H + kt * 32 + quad * 8);
    const float pbias = LD<BT>::ld1(bp, m16);

#pragma unroll
    for (int s = 0; s < 4; ++s) {
        f32x4 pa = vzero;
#pragma unroll
        for (int kt = 0; kt < 4; ++kt)
            pa = __builtin_amdgcn_mfma_f32_16x16x32_bf16(a3[s][kt].v, bpf[kt].v, pa, 0, 0, 0);
#pragma unroll
        for (int r = 0; r < 4; ++r) {
            const int row = rowblk + s * 16 + quad * 4 + r;
            LD<MT>::st1(out, (size_t)row * NA + m16, pa[r] + pbias);
        }
    }

    Frag bvf[4];
#pragma unroll
    for (int kt = 0; kt < 4; ++kt) {
        if (m16 == 0) bvf[kt] = LD<MT>::load8(Wv, kt * 32 + quad * 8);
        else          bvf[kt].u = make_uint4(0u, 0u, 0u, 0u);
    }
    const float vbias = LD<BT>::ld1(bv, 0);

#pragma unroll
    for (int s = 0; s < 4; ++s) {
        f32x4 va = vzero;
#pragma unroll
        for (int kt = 0; kt < 4; ++kt)
            va = __builtin_amdgcn_mfma_f32_16x16x32_bf16(a3[s][kt].v, bvf[kt].v, va, 0, 0, 0);
        if (m16 == 0) {
#pragma unroll
            for (int r = 0; r < 4; ++r) {
                const int row = rowblk + s * 16 + quad * 4 + r;
                LD<MT>::st1(out, (size_t)BATCH * NA + row, va[r] + vbias);
            }
        }
    }
}

extern "C" __global__ __launch_bounds__(128)
void lstm_fused(const void* x, const void* Wih0, const void* bih0, const void* bhh0,
                const void* Wih1, const void* bih1, const void* bhh1,
                const void* Wp, const void* bp, const void* Wv, const void* bv,
                void* out)
{
    __shared__ __align__(16) __hip_bfloat16 hbuf[2][64 * HPAD];

    const int wave   = threadIdx.x >> 6;
    const int lane   = threadIdx.x & 63;
    const int rowblk = (blockIdx.x * 2 + wave) * 64;
    __hip_bfloat16* hb = &hbuf[wave][0];

    // ---- runtime dtype probe (wave-uniform, deterministic) ----
    // f32 data misread as bf16 halfwords shows exponent >= 0x88 (|v| >= 512)
    // with overwhelming probability; true bf16 N(0,1)/U(+-0.09) never does.
    const unsigned short ux = reinterpret_cast<const unsigned short*>(x)[lane];
    const unsigned short ub = reinterpret_cast<const unsigned short*>(bih0)[lane];
    const bool x_is_f32 = __ballot(((ux >> 7) & 0xFF) >= 0x88) != 0ull;
    const bool b_is_f32 = __ballot(((ub >> 7) & 0xFF) >= 0x88) != 0ull;

    if (x_is_f32)
        run_net<float, float>(x, Wih0, bih0, bhh0, Wih1, bih1, bhh1,
                              Wp, bp, Wv, bv, out, hb, lane, rowblk);
    else if (b_is_f32)
        run_net<__hip_bfloat16, float>(x, Wih0, bih0, bhh0, Wih1, bih1, bhh1,
                                       Wp, bp, Wv, bv, out, hb, lane, rowblk);
    else
        run_net<__hip_bfloat16, __hip_bfloat16>(x, Wih0, bih0, bhh0, Wih1, bih1, bhh1,
                                                Wp, bp, Wv, bv, out, hb, lane, rowblk);
}

extern "C" void kernel_launch(void* const* d_in, const int* in_sizes, int n_in,
                              void* d_out, int out_size, void* d_ws, size_t ws_size,
                              hipStream_t stream) {
    // setup_inputs order: x, Wih0, Whh0, bih0, bhh0, Wih1, Whh1, bih1, bhh1, Wp, bp, Wv, bv
    // Whh0 (idx 2) and Whh1 (idx 6) are dead: h_prev == 0.
    lstm_fused<<<dim3(BATCH / 128), dim3(128), 0, stream>>>(
        d_in[0], d_in[1], d_in[3], d_in[4],
        d_in[5], d_in[7], d_in[8],
        d_in[9], d_in[10], d_in[11], d_in[12],
        d_out);
}

// Round 3
// 152.287 us; speedup vs baseline: 1.1670x; 1.1670x over previous
//
#include <hip/hip_runtime.h>
#include <hip/hip_bf16.h>

#define BATCH 65536
#define IN    64
#define H     128
#define NA    16
#define HPAD  136   // 128 + 8 pad

typedef __bf16 bf16x8 __attribute__((ext_vector_type(8)));
typedef float  f32x4  __attribute__((ext_vector_type(4)));

union Frag { uint4 u; bf16x8 v; };

#if __has_builtin(__builtin_amdgcn_exp2f)
#define EXP2F(x) __builtin_amdgcn_exp2f(x)
#else
#define EXP2F(x) exp2f(x)
#endif
#if __has_builtin(__builtin_amdgcn_rcpf)
#define RCPF(x) __builtin_amdgcn_rcpf(x)
#else
#define RCPF(x) (1.0f / (x))
#endif

// sigmoid/tanh with exactly one v_exp + one v_rcp each (bf16-accuracy is ample)
__device__ __forceinline__ float sigm(float x) {
    return RCPF(1.0f + EXP2F(-1.442695041f * x));
}
__device__ __forceinline__ float tanh_(float x) {
    return 1.0f - 2.0f * RCPF(1.0f + EXP2F(2.885390082f * x));
}

// ---- dtype-generic loads (convert to bf16 fragments / f32 scalars) ----
template<typename T> struct LD;
template<> struct LD<__hip_bfloat16> {
    static __device__ __forceinline__ Frag load8(const void* base, size_t off) {
        Frag f;
        f.u = *reinterpret_cast<const uint4*>(reinterpret_cast<const __hip_bfloat16*>(base) + off);
        return f;
    }
    static __device__ __forceinline__ float ld1(const void* base, size_t i) {
        return __bfloat162float(reinterpret_cast<const __hip_bfloat16*>(base)[i]);
    }
    static __device__ __forceinline__ void st1(void* base, size_t i, float v) {
        reinterpret_cast<__hip_bfloat16*>(base)[i] = __float2bfloat16(v);
    }
};
template<> struct LD<float> {
    static __device__ __forceinline__ Frag load8(const void* base, size_t off) {
        const float* p = reinterpret_cast<const float*>(base) + off;
        float4 a = *reinterpret_cast<const float4*>(p);
        float4 b = *reinterpret_cast<const float4*>(p + 4);
        Frag f;
        f.v[0] = (__bf16)a.x; f.v[1] = (__bf16)a.y; f.v[2] = (__bf16)a.z; f.v[3] = (__bf16)a.w;
        f.v[4] = (__bf16)b.x; f.v[5] = (__bf16)b.y; f.v[6] = (__bf16)b.z; f.v[7] = (__bf16)b.w;
        return f;
    }
    static __device__ __forceinline__ float ld1(const void* base, size_t i) {
        return reinterpret_cast<const float*>(base)[i];
    }
    static __device__ __forceinline__ void st1(void* base, size_t i, float v) {
        reinterpret_cast<float*>(base)[i] = v;
    }
};

// Block = 256 threads = 4 waves, owns 64 batch rows.
// N-split: wave w computes c-tiles {2w, 2w+1} (x 3 gates) of each LSTM layer;
// h0/h1 are assembled in block LDS and shared across waves via barriers.
template<typename MT, typename BT>
__device__ __forceinline__ void run_net(
    const void* x, const void* Wih0, const void* bih0, const void* bhh0,
    const void* Wih1, const void* bih1, const void* bhh1,
    const void* Wp, const void* bp, const void* Wv, const void* bv,
    void* out, __hip_bfloat16* hb0, __hip_bfloat16* hb1,
    int wave, int lane, int rowblk)
{
    const int m16  = lane & 15;
    const int quad = lane >> 4;
    const int c0   = wave * 2;
    const f32x4 vzero = {0.f, 0.f, 0.f, 0.f};
    const int kGoff[3] = {0, 2 * H, 3 * H};   // gates i, g, o (f dead: c_prev = 0)

    // ===== GEMM1: gates0 = x @ Wih0[igo]^T ; h0 -> LDS =====
    Frag a1[4][2];
#pragma unroll
    for (int s = 0; s < 4; ++s)
#pragma unroll
        for (int kt = 0; kt < 2; ++kt)
            a1[s][kt] = LD<MT>::load8(x, (size_t)(rowblk + s * 16 + m16) * IN + kt * 32 + quad * 8);

#pragma unroll
    for (int ci = 0; ci < 2; ++ci) {
        const int c = c0 + ci;
        f32x4 acc[3][4];
#pragma unroll
        for (int G = 0; G < 3; ++G)
#pragma unroll
            for (int s = 0; s < 4; ++s) acc[G][s] = vzero;

#pragma unroll
        for (int G = 0; G < 3; ++G) {
            const int wrow = kGoff[G] + c * 16 + m16;
#pragma unroll
            for (int kt = 0; kt < 2; ++kt) {
                Frag b = LD<MT>::load8(Wih0, (size_t)wrow * IN + kt * 32 + quad * 8);
#pragma unroll
                for (int s = 0; s < 4; ++s)
                    acc[G][s] = __builtin_amdgcn_mfma_f32_16x16x32_bf16(a1[s][kt].v, b.v, acc[G][s], 0, 0, 0);
            }
        }
        float bi[3];
#pragma unroll
        for (int G = 0; G < 3; ++G) {
            const int n = kGoff[G] + c * 16 + m16;
            bi[G] = LD<BT>::ld1(bih0, n) + LD<BT>::ld1(bhh0, n);
        }
#pragma unroll
        for (int s = 0; s < 4; ++s)
#pragma unroll
            for (int r = 0; r < 4; ++r) {
                const float ii = sigm (acc[0][s][r] + bi[0]);
                const float gg = tanh_(acc[1][s][r] + bi[1]);
                const float oo = sigm (acc[2][s][r] + bi[2]);
                const float h  = oo * tanh_(ii * gg);
                hb0[(s * 16 + quad * 4 + r) * HPAD + c * 16 + m16] = __float2bfloat16(h);
            }
    }
    __syncthreads();

    // ===== GEMM2: gates1 = h0 @ Wih1[igo]^T ; h1 -> LDS =====
    Frag a2[4][4];
#pragma unroll
    for (int s = 0; s < 4; ++s)
#pragma unroll
        for (int kt = 0; kt < 4; ++kt)
            a2[s][kt].u = *reinterpret_cast<const uint4*>(hb0 + (s * 16 + m16) * HPAD + kt * 32 + quad * 8);

#pragma unroll
    for (int ci = 0; ci < 2; ++ci) {
        const int c = c0 + ci;
        f32x4 acc[3][4];
#pragma unroll
        for (int G = 0; G < 3; ++G)
#pragma unroll
            for (int s = 0; s < 4; ++s) acc[G][s] = vzero;

#pragma unroll
        for (int G = 0; G < 3; ++G) {
            const int wrow = kGoff[G] + c * 16 + m16;
#pragma unroll
            for (int kt = 0; kt < 4; ++kt) {
                Frag b = LD<MT>::load8(Wih1, (size_t)wrow * H + kt * 32 + quad * 8);
#pragma unroll
                for (int s = 0; s < 4; ++s)
                    acc[G][s] = __builtin_amdgcn_mfma_f32_16x16x32_bf16(a2[s][kt].v, b.v, acc[G][s], 0, 0, 0);
            }
        }
        float bi[3];
#pragma unroll
        for (int G = 0; G < 3; ++G) {
            const int n = kGoff[G] + c * 16 + m16;
            bi[G] = LD<BT>::ld1(bih1, n) + LD<BT>::ld1(bhh1, n);
        }
#pragma unroll
        for (int s = 0; s < 4; ++s)
#pragma unroll
            for (int r = 0; r < 4; ++r) {
                const float ii = sigm (acc[0][s][r] + bi[0]);
                const float gg = tanh_(acc[1][s][r] + bi[1]);
                const float oo = sigm (acc[2][s][r] + bi[2]);
                const float h  = oo * tanh_(ii * gg);
                hb1[(s * 16 + quad * 4 + r) * HPAD + c * 16 + m16] = __float2bfloat16(h);
            }
    }
    __syncthreads();

    // ===== Heads: wave w takes M-subtile s = w (16 rows) =====
    Frag a3[4];
#pragma unroll
    for (int kt = 0; kt < 4; ++kt)
        a3[kt].u = *reinterpret_cast<const uint4*>(hb1 + (wave * 16 + m16) * HPAD + kt * 32 + quad * 8);

    Frag bpf[4];
#pragma unroll
    for (int kt = 0; kt < 4; ++kt)
        bpf[kt] = LD<MT>::load8(Wp, (size_t)m16 * H + kt * 32 + quad * 8);
    const float pbias = LD<BT>::ld1(bp, m16);

    f32x4 pa = vzero;
#pragma unroll
    for (int kt = 0; kt < 4; ++kt)
        pa = __builtin_amdgcn_mfma_f32_16x16x32_bf16(a3[kt].v, bpf[kt].v, pa, 0, 0, 0);
#pragma unroll
    for (int r = 0; r < 4; ++r) {
        const int row = rowblk + wave * 16 + quad * 4 + r;
        LD<MT>::st1(out, (size_t)row * NA + m16, pa[r] + pbias);
    }

    Frag bvf[4];
#pragma unroll
    for (int kt = 0; kt < 4; ++kt) {
        if (m16 == 0) bvf[kt] = LD<MT>::load8(Wv, kt * 32 + quad * 8);
        else          bvf[kt].u = make_uint4(0u, 0u, 0u, 0u);
    }
    const float vbias = LD<BT>::ld1(bv, 0);

    f32x4 va = vzero;
#pragma unroll
    for (int kt = 0; kt < 4; ++kt)
        va = __builtin_amdgcn_mfma_f32_16x16x32_bf16(a3[kt].v, bvf[kt].v, va, 0, 0, 0);
    if (m16 == 0) {
#pragma unroll
        for (int r = 0; r < 4; ++r) {
            const int row = rowblk + wave * 16 + quad * 4 + r;
            LD<MT>::st1(out, (size_t)BATCH * NA + row, va[r] + vbias);
        }
    }
}

extern "C" __global__ __launch_bounds__(256, 4)
void lstm_fused(const void* x, const void* Wih0, const void* bih0, const void* bhh0,
                const void* Wih1, const void* bih1, const void* bhh1,
                const void* Wp, const void* bp, const void* Wv, const void* bv,
                void* out)
{
    __shared__ __align__(16) __hip_bfloat16 hb0[64 * HPAD];
    __shared__ __align__(16) __hip_bfloat16 hb1[64 * HPAD];

    const int wave   = threadIdx.x >> 6;
    const int lane   = threadIdx.x & 63;
    const int rowblk = blockIdx.x * 64;

    // ---- runtime dtype probe (grid-uniform, deterministic, graph-safe) ----
    const unsigned short ux = reinterpret_cast<const unsigned short*>(x)[lane];
    const unsigned short ub = reinterpret_cast<const unsigned short*>(bih0)[lane];
    const bool x_is_f32 = __ballot(((ux >> 7) & 0xFF) >= 0x88) != 0ull;
    const bool b_is_f32 = __ballot(((ub >> 7) & 0xFF) >= 0x88) != 0ull;

    if (x_is_f32)
        run_net<float, float>(x, Wih0, bih0, bhh0, Wih1, bih1, bhh1,
                              Wp, bp, Wv, bv, out, hb0, hb1, wave, lane, rowblk);
    else if (b_is_f32)
        run_net<__hip_bfloat16, float>(x, Wih0, bih0, bhh0, Wih1, bih1, bhh1,
                                       Wp, bp, Wv, bv, out, hb0, hb1, wave, lane, rowblk);
    else
        run_net<__hip_bfloat16, __hip_bfloat16>(x, Wih0, bih0, bhh0, Wih1, bih1, bhh1,
                                                Wp, bp, Wv, bv, out, hb0, hb1, wave, lane, rowblk);
}

extern "C" void kernel_launch(void* const* d_in, const int* in_sizes, int n_in,
                              void* d_out, int out_size, void* d_ws, size_t ws_size,
                              hipStream_t stream) {
    // setup_inputs order: x, Wih0, Whh0, bih0, bhh0, Wih1, Whh1, bih1, bhh1, Wp, bp, Wv, bv
    // Whh0 (idx 2) / Whh1 (idx 6) dead (h_prev = 0); f-gate dead (c_prev = 0).
    lstm_fused<<<dim3(BATCH / 64), dim3(256), 0, stream>>>(
        d_in[0], d_in[1], d_in[3], d_in[4],
        d_in[5], d_in[7], d_in[8],
        d_in[9], d_in[10], d_in[11], d_in[12],
        d_out);
}

// Round 6
// 146.646 us; speedup vs baseline: 1.2119x; 1.0385x over previous
//
#include <hip/hip_runtime.h>
#include <hip/hip_bf16.h>

#define BATCH 65536
#define IN    64
#define H     128
#define NA    16
#define HPAD  136   // 128 + 8 pad (bf16 elems); 272 B row stride, 16B-aligned

typedef __bf16 bf16x8 __attribute__((ext_vector_type(8)));
typedef float  f32x4  __attribute__((ext_vector_type(4)));

union Frag { uint4 u; bf16x8 v; };

#define EXP2F(v) __builtin_amdgcn_exp2f(v)
#define RCPF(v)  __builtin_amdgcn_rcpf(v)
#define K1 1.442695041f   // log2(e)
#define K2 2.885390082f   // 2*log2(e)

// All tensors are FLOAT32 (proven R2: WRITE_SIZE 4352 KB == 65536*17*4 B f32
// output, and R2/R3 passed via the <float,float> template path; the bench's
// "bf16" label is a hardcoded f-string). Load f32, convert to bf16 frags.
__device__ __forceinline__ Frag g8f(const float* p) {
    const float4 a = *reinterpret_cast<const float4*>(p);
    const float4 b = *reinterpret_cast<const float4*>(p + 4);
    Frag f;
    f.v[0] = (__bf16)a.x; f.v[1] = (__bf16)a.y; f.v[2] = (__bf16)a.z; f.v[3] = (__bf16)a.w;
    f.v[4] = (__bf16)b.x; f.v[5] = (__bf16)b.y; f.v[6] = (__bf16)b.z; f.v[7] = (__bf16)b.w;
    return f;
}

__device__ __forceinline__ float clamp30(float v) {
    return __builtin_fminf(__builtin_fmaxf(v, -30.0f), 30.0f);
}

// h = sigmoid(o) * tanh(sigmoid(i) * tanh(g)); f-gate dead (c_prev = 0).
// 4 exp + 2 rcp; preacts clamped to +-30 => exp2 args <= 87 < 128: no inf,
// and sigma/tanh are saturated long before +-30 so the clamp is exact.
__device__ __forceinline__ float lstm_h(float ip, float gp, float op) {
    ip = clamp30(ip); gp = clamp30(gp); op = clamp30(op);
    const float Ei = EXP2F(-K1 * ip);
    const float Eg = EXP2F( K2 * gp);
    const float c2 = (Eg - 1.0f) * RCPF((1.0f + Ei) * (Eg + 1.0f));
    const float Eo = EXP2F(-K1 * op);
    const float Ec = EXP2F( K2 * c2);
    return (Ec - 1.0f) * RCPF((1.0f + Eo) * (Ec + 1.0f));
}

// Block = 256 threads = 4 waves, owns 64 batch rows. Wave w computes
// c-tiles {2w, 2w+1} x 3 gates; h0/h1 shared via block LDS (bf16) + barriers.
__global__ __launch_bounds__(256)
void lstm_fused(const float* __restrict__ x,
                const float* __restrict__ Wih0,
                const float* __restrict__ bih0,
                const float* __restrict__ bhh0,
                const float* __restrict__ Wih1,
                const float* __restrict__ bih1,
                const float* __restrict__ bhh1,
                const float* __restrict__ Wp,
                const float* __restrict__ bp,
                const float* __restrict__ Wv,
                const float* __restrict__ bv,
                float* __restrict__ out)
{
    __shared__ __align__(16) __hip_bfloat16 hb0[64 * HPAD];
    __shared__ __align__(16) __hip_bfloat16 hb1[64 * HPAD];

    const int wave   = threadIdx.x >> 6;
    const int lane   = threadIdx.x & 63;
    const int m16    = lane & 15;
    const int quad   = lane >> 4;
    const int c0     = wave * 2;
    const int rowblk = blockIdx.x * 64;
    const f32x4 vzero = {0.f, 0.f, 0.f, 0.f};
    const int kGoff[3] = {0, 2 * H, 3 * H};   // gate rows: i, g, o

    // ===== GEMM1: gates0 = x @ Wih0[igo]^T ; h0 -> LDS =====
    Frag a1[4][2];
#pragma unroll
    for (int s = 0; s < 4; ++s)
#pragma unroll
        for (int kt = 0; kt < 2; ++kt)
            a1[s][kt] = g8f(x + (size_t)(rowblk + s * 16 + m16) * IN + kt * 32 + quad * 8);

#pragma unroll
    for (int ci = 0; ci < 2; ++ci) {
        const int c = c0 + ci;
        f32x4 acc[3][4];
#pragma unroll
        for (int G = 0; G < 3; ++G)
#pragma unroll
            for (int s = 0; s < 4; ++s) acc[G][s] = vzero;

#pragma unroll
        for (int kt = 0; kt < 2; ++kt) {
            Frag b[3];
#pragma unroll
            for (int G = 0; G < 3; ++G)
                b[G] = g8f(Wih0 + (size_t)(kGoff[G] + c * 16 + m16) * IN + kt * 32 + quad * 8);
#pragma unroll
            for (int G = 0; G < 3; ++G)
#pragma unroll
                for (int s = 0; s < 4; ++s)
                    acc[G][s] = __builtin_amdgcn_mfma_f32_16x16x32_bf16(a1[s][kt].v, b[G].v, acc[G][s], 0, 0, 0);
        }

        float bi[3];
#pragma unroll
        for (int G = 0; G < 3; ++G) {
            const int n = kGoff[G] + c * 16 + m16;
            bi[G] = bih0[n] + bhh0[n];
        }
#pragma unroll
        for (int s = 0; s < 4; ++s)
#pragma unroll
            for (int r = 0; r < 4; ++r) {
                const float h = lstm_h(acc[0][s][r] + bi[0],
                                       acc[1][s][r] + bi[1],
                                       acc[2][s][r] + bi[2]);
                hb0[(s * 16 + quad * 4 + r) * HPAD + c * 16 + m16] = __float2bfloat16(h);
            }
    }
    __syncthreads();

    // ===== GEMM2: gates1 = h0 @ Wih1[igo]^T ; h1 -> LDS =====
#pragma unroll
    for (int ci = 0; ci < 2; ++ci) {
        const int c = c0 + ci;
        f32x4 acc[3][4];
#pragma unroll
        for (int G = 0; G < 3; ++G)
#pragma unroll
            for (int s = 0; s < 4; ++s) acc[G][s] = vzero;

#pragma unroll
        for (int kt = 0; kt < 4; ++kt) {
            Frag a[4];
#pragma unroll
            for (int s = 0; s < 4; ++s)
                a[s].u = *reinterpret_cast<const uint4*>(hb0 + (s * 16 + m16) * HPAD + kt * 32 + quad * 8);
            Frag b[3];
#pragma unroll
            for (int G = 0; G < 3; ++G)
                b[G] = g8f(Wih1 + (size_t)(kGoff[G] + c * 16 + m16) * H + kt * 32 + quad * 8);
#pragma unroll
            for (int G = 0; G < 3; ++G)
#pragma unroll
                for (int s = 0; s < 4; ++s)
                    acc[G][s] = __builtin_amdgcn_mfma_f32_16x16x32_bf16(a[s].v, b[G].v, acc[G][s], 0, 0, 0);
        }

        float bi[3];
#pragma unroll
        for (int G = 0; G < 3; ++G) {
            const int n = kGoff[G] + c * 16 + m16;
            bi[G] = bih1[n] + bhh1[n];
        }
#pragma unroll
        for (int s = 0; s < 4; ++s)
#pragma unroll
            for (int r = 0; r < 4; ++r) {
                const float h = lstm_h(acc[0][s][r] + bi[0],
                                       acc[1][s][r] + bi[1],
                                       acc[2][s][r] + bi[2]);
                hb1[(s * 16 + quad * 4 + r) * HPAD + c * 16 + m16] = __float2bfloat16(h);
            }
    }
    __syncthreads();

    // ===== Heads: wave w takes M-subtile s = w (16 rows) =====
    Frag a3[4];
#pragma unroll
    for (int kt = 0; kt < 4; ++kt)
        a3[kt].u = *reinterpret_cast<const uint4*>(hb1 + (wave * 16 + m16) * HPAD + kt * 32 + quad * 8);

    Frag bpf[4];
#pragma unroll
    for (int kt = 0; kt < 4; ++kt)
        bpf[kt] = g8f(Wp + (size_t)m16 * H + kt * 32 + quad * 8);
    const float pbias = bp[m16];

    f32x4 pa = vzero;
#pragma unroll
    for (int kt = 0; kt < 4; ++kt)
        pa = __builtin_amdgcn_mfma_f32_16x16x32_bf16(a3[kt].v, bpf[kt].v, pa, 0, 0, 0);
#pragma unroll
    for (int r = 0; r < 4; ++r) {
        const int row = rowblk + wave * 16 + quad * 4 + r;
        out[(size_t)row * NA + m16] = pa[r] + pbias;
    }

    Frag bvf[4];
#pragma unroll
    for (int kt = 0; kt < 4; ++kt) {
        if (m16 == 0) bvf[kt] = g8f(Wv + kt * 32 + quad * 8);
        else          bvf[kt].u = make_uint4(0u, 0u, 0u, 0u);
    }
    const float vbias = bv[0];

    f32x4 va = vzero;
#pragma unroll
    for (int kt = 0; kt < 4; ++kt)
        va = __builtin_amdgcn_mfma_f32_16x16x32_bf16(a3[kt].v, bvf[kt].v, va, 0, 0, 0);
    if (m16 == 0) {
#pragma unroll
        for (int r = 0; r < 4; ++r) {
            const int row = rowblk + wave * 16 + quad * 4 + r;
            out[(size_t)BATCH * NA + row] = va[r] + vbias;
        }
    }
}

extern "C" void kernel_launch(void* const* d_in, const int* in_sizes, int n_in,
                              void* d_out, int out_size, void* d_ws, size_t ws_size,
                              hipStream_t stream) {
    // setup_inputs order: x, Wih0, Whh0, bih0, bhh0, Wih1, Whh1, bih1, bhh1, Wp, bp, Wv, bv
    // Whh0 (idx 2) / Whh1 (idx 6) dead (h_prev = 0); f-gate dead (c_prev = 0).
    // ALL tensors float32 (R5 post-mortem: WRITE_SIZE == f32 out size exactly;
    // R2/R3 passed via the all-f32 template path).
    lstm_fused<<<dim3(BATCH / 64), dim3(256), 0, stream>>>(
        (const float*)d_in[0], (const float*)d_in[1],
        (const float*)d_in[3], (const float*)d_in[4],
        (const float*)d_in[5], (const float*)d_in[7],
        (const float*)d_in[8], (const float*)d_in[9],
        (const float*)d_in[10], (const float*)d_in[11],
        (const float*)d_in[12], (float*)d_out);
}